// Round 7
// baseline (8850.349 us; speedup 1.0000x reference)
//
#include <hip/hip_runtime.h>

#define TT 512
#define HH 50

__device__ __forceinline__ float sigf(float x) {
    return 1.0f / (1.0f + __expf(-x));
}
__device__ __forceinline__ float tanhfast(float x) {
    // tanh(x) = 1 - 2/(e^{2x}+1); exact limits at +-inf, branch-free
    return 1.0f - 2.0f / (__expf(2.0f * x) + 1.0f);
}

// 2 parallel 50-length dot products: a_g += sum_k w[g][k] * hp[k]
// hp is an LDS pointer, uniform across the wave (broadcast reads, conflict-free).
__device__ __forceinline__ void dot50x2(const float (&w)[2][HH], const float* hp,
                                        float& a0, float& a1) {
#pragma unroll
    for (int q = 0; q < 12; ++q) {
        float4 h4 = *reinterpret_cast<const float4*>(&hp[4 * q]);
        a0 = fmaf(h4.x, w[0][4 * q + 0], a0);
        a0 = fmaf(h4.y, w[0][4 * q + 1], a0);
        a0 = fmaf(h4.z, w[0][4 * q + 2], a0);
        a0 = fmaf(h4.w, w[0][4 * q + 3], a0);
        a1 = fmaf(h4.x, w[1][4 * q + 0], a1);
        a1 = fmaf(h4.y, w[1][4 * q + 1], a1);
        a1 = fmaf(h4.z, w[1][4 * q + 2], a1);
        a1 = fmaf(h4.w, w[1][4 * q + 3], a1);
    }
    float2 h2 = *reinterpret_cast<const float2*>(&hp[48]);
    a0 = fmaf(h2.x, w[0][48], a0); a0 = fmaf(h2.y, w[0][49], a0);
    a1 = fmaf(h2.x, w[1][48], a1); a1 = fmaf(h2.y, w[1][49], a1);
}

// Fused register pins: 25 simultaneous "+v" operands per asm block.
#define PIN25(A, O) asm volatile("" : \
    "+v"(A[O+0]),"+v"(A[O+1]),"+v"(A[O+2]),"+v"(A[O+3]),"+v"(A[O+4]), \
    "+v"(A[O+5]),"+v"(A[O+6]),"+v"(A[O+7]),"+v"(A[O+8]),"+v"(A[O+9]), \
    "+v"(A[O+10]),"+v"(A[O+11]),"+v"(A[O+12]),"+v"(A[O+13]),"+v"(A[O+14]), \
    "+v"(A[O+15]),"+v"(A[O+16]),"+v"(A[O+17]),"+v"(A[O+18]),"+v"(A[O+19]), \
    "+v"(A[O+20]),"+v"(A[O+21]),"+v"(A[O+22]),"+v"(A[O+23]),"+v"(A[O+24]))

// One block = one batch element, 6 waves = 3 pairs:
//   p=0: layer0 recurrent (W_hh0), p=1: layer1 input matmul (W_ih1),
//   p=2: layer1 recurrent (W_hh1); s = gate half (i,f)/(g,o): 100 weights/lane.
//
// LDS OCCUPANCY GOVERNOR (round-6 lever): occ_pad brings LDS to ~72 KB/block
// -> exactly 2 blocks/CU (144 KB <= 160 KB; 3 blocks would need 216 KB).
// The backend computes its waves/EU cap from LDS at compile time: 12 waves/CU
// = 3 waves/EU -> register budget ~168, and shrinking to 64 VGPRs no longer
// buys ANY occupancy. This removes the heuristic's incentive to AGPR-park the
// 104 stationary values (rounds 2-5: VGPR_Count pinned at 64, accvgpr shuttle
// = measured 2.5x VALU inflation).
// Tripwires: VGPR_Count <= 64 => allocator unbeatable at source level, pivot
// to split-bf16 MFMA design; WRITE_SIZE in MBs => scratch spill.
__global__ __launch_bounds__(384)
void lstm2_pipeline6_kernel(const float* __restrict__ x,
                            const float* __restrict__ W_ih0, const float* __restrict__ W_hh0,
                            const float* __restrict__ b_ih0, const float* __restrict__ b_hh0,
                            const float* __restrict__ W_ih1, const float* __restrict__ W_hh1,
                            const float* __restrict__ b_ih1, const float* __restrict__ b_hh1,
                            const float* __restrict__ W1, const float* __restrict__ b1,
                            const float* __restrict__ W2, const float* __restrict__ b2,
                            const float* __restrict__ W3, const float* __restrict__ b3,
                            float* __restrict__ out)
{
    const int b    = blockIdx.x;
    const int tid  = threadIdx.x;
    const int wid  = tid >> 6;     // 0..5
    const int p    = wid >> 1;     // matrix: 0=W_hh0, 1=W_ih1, 2=W_hh1
    const int s    = wid & 1;      // gate half: 0 -> (i,f), 1 -> (g,o)
    const int lane = tid & 63;
    const int js   = (lane < HH) ? lane : 0;   // clamped unit index
    const bool act = (lane < HH);

    __shared__ __align__(16) float h0[52];         // layer0 hidden
    __shared__ __align__(16) float h1[52];         // layer1 hidden
    __shared__ __align__(16) float G0[4][52];      // layer0 gate pre-activations [gate][unit]
    __shared__ __align__(16) float G2[4][52];      // layer1 gate pre-activations
    __shared__ __align__(16) float Bx[2][4][52];   // xg1 double buffer [buf][gate][unit]
    __shared__ float D1[32];
    __shared__ float D2[16];
    __shared__ float occ_pad[17000];               // 68 KB occupancy governor

    // Reference occ_pad so it isn't eliminated (one volatile store per block).
    if (tid == 0) *(volatile float*)&occ_pad[0] = 0.0f;

    if (tid < 52) { h0[tid] = 0.0f; h1[tid] = 0.0f; }

    // --- Stationary weights: lane j of wave (p,s) holds rows {2s*50+j, (2s+1)*50+j} ---
    const float* Wm = (p == 0) ? W_hh0 : (p == 1) ? W_ih1 : W_hh1;
    float w[2][HH];
#pragma unroll
    for (int g = 0; g < 2; ++g) {
        const int row = (2 * s + g) * HH + js;
#pragma unroll
        for (int k = 0; k < HH; ++k)
            w[g][k] = Wm[row * HH + k];
    }

    float bias[2], wx[2];
#pragma unroll
    for (int g = 0; g < 2; ++g) {
        const int r = (2 * s + g) * HH + js;
        bias[g] = (p == 0) ? (b_ih0[r] + b_hh0[r]) : (p == 1) ? b_ih1[r] : b_hh1[r];
        wx[g]   = (p == 0) ? W_ih0[r] : 0.0f;
    }

    float c_st = 0.0f;                 // cell state (p0s0: layer0, p2s0: layer1)
    const float* xrow = x + (size_t)b * TT;
    float x_cur = (p == 0) ? xrow[0] : 0.0f;
    float x_nxt = 0.0f;

    __syncthreads();

    for (int tau = 0; tau < TT + 2; ++tau) {
        // Per-tick fused pins. Zero instructions if the home is an arch VGPR.
        PIN25(w[0], 0); PIN25(w[0], 25);
        PIN25(w[1], 0); PIN25(w[1], 25);
        asm volatile("" : "+v"(bias[0]), "+v"(bias[1]), "+v"(wx[0]), "+v"(wx[1]));

        // ================= M phase: matmuls =================
        if (p == 0) {
            if (tau < TT) {                         // step t = tau, reads h0(t-1)
                if (tau + 1 < TT) x_nxt = xrow[tau + 1];
                float a0 = fmaf(x_cur, wx[0], bias[0]);
                float a1 = fmaf(x_cur, wx[1], bias[1]);
                dot50x2(w, h0, a0, a1);
                if (act) { G0[2 * s][lane] = a0; G0[2 * s + 1][lane] = a1; }
                x_cur = x_nxt;
            }
        } else if (p == 1) {
            if (tau >= 1 && tau <= TT) {            // xg1 for step t = tau-1, reads h0(t)
                float a0 = bias[0], a1 = bias[1];
                dot50x2(w, h0, a0, a1);
                if (act) {
                    Bx[tau & 1][2 * s][lane]     = a0;
                    Bx[tau & 1][2 * s + 1][lane] = a1;
                }
            }
        } else {
            if (tau >= 2) {                         // step t = tau-2, reads h1(t-1), xg1(t)
                const int buf = (tau + 1) & 1;
                float a0 = bias[0] + Bx[buf][2 * s][js];
                float a1 = bias[1] + Bx[buf][2 * s + 1][js];
                dot50x2(w, h1, a0, a1);
                if (act) { G2[2 * s][lane] = a0; G2[2 * s + 1][lane] = a1; }
            }
        }
        __syncthreads();
        // ================= P phase: pointwise =================
        if (s == 0 && act) {
            if (p == 0 && tau < TT) {
                float i = sigf(G0[0][lane]);
                float f = sigf(G0[1][lane]);
                float g = tanhfast(G0[2][lane]);
                float o = sigf(G0[3][lane]);
                c_st = fmaf(f, c_st, i * g);
                h0[lane] = o * tanhfast(c_st);
            } else if (p == 2 && tau >= 2) {
                float i = sigf(G2[0][lane]);
                float f = sigf(G2[1][lane]);
                float g = tanhfast(G2[2][lane]);
                float o = sigf(G2[3][lane]);
                c_st = fmaf(f, c_st, i * g);
                h1[lane] = o * tanhfast(c_st);
            }
        }
        __syncthreads();
    }

    // --- MLP head on final h1 (in LDS); wave 0 computes, barriers hit by all ---
    if (wid == 0 && lane < 32) {
        float z = b1[lane];
#pragma unroll
        for (int k = 0; k < HH; ++k) z = fmaf(W1[lane * HH + k], h1[k], z);
        D1[lane] = fmaxf(z, 0.0f);
    }
    __syncthreads();
    if (wid == 0 && lane < 16) {
        float z = b2[lane];
#pragma unroll
        for (int k = 0; k < 32; ++k) z = fmaf(W2[lane * 32 + k], D1[k], z);
        D2[lane] = fmaxf(z, 0.0f);
    }
    __syncthreads();
    if (wid == 0 && lane == 0) {
        float z = b3[0];
#pragma unroll
        for (int k = 0; k < 16; ++k) z = fmaf(W3[k], D2[k], z);
        out[b] = z;
    }
}

extern "C" void kernel_launch(void* const* d_in, const int* in_sizes, int n_in,
                              void* d_out, int out_size, void* d_ws, size_t ws_size,
                              hipStream_t stream) {
    const float* x     = (const float*)d_in[0];
    const float* W_ih0 = (const float*)d_in[1];
    const float* W_hh0 = (const float*)d_in[2];
    const float* b_ih0 = (const float*)d_in[3];
    const float* b_hh0 = (const float*)d_in[4];
    const float* W_ih1 = (const float*)d_in[5];
    const float* W_hh1 = (const float*)d_in[6];
    const float* b_ih1 = (const float*)d_in[7];
    const float* b_hh1 = (const float*)d_in[8];
    const float* W1    = (const float*)d_in[9];
    const float* b1    = (const float*)d_in[10];
    const float* W2    = (const float*)d_in[11];
    const float* b2    = (const float*)d_in[12];
    const float* W3    = (const float*)d_in[13];
    const float* b3    = (const float*)d_in[14];

    const int B = in_sizes[0] / TT;   // x is [B, T, 1]

    lstm2_pipeline6_kernel<<<dim3(B), dim3(384), 0, stream>>>(
        x, W_ih0, W_hh0, b_ih0, b_hh0, W_ih1, W_hh1, b_ih1, b_hh1,
        W1, b1, W2, b2, W3, b3, (float*)d_out);
}

// Round 8
// 1211.164 us; speedup vs baseline: 7.3073x; 7.3073x over previous
//
#include <hip/hip_runtime.h>

#define TT 512
#define HH 50
#define BT 16          // batch rows per block (MFMA M)
#define AK 136         // A-buffer row stride in bf16 elems (272 B, 16B-aligned, 2-way banks)
#define GS 420         // gates row stride in floats
#define XC 64          // x staging chunk (ticks)
#define XSS 68         // x chunk row stride

typedef __attribute__((ext_vector_type(8))) short bf16x8;
typedef __attribute__((ext_vector_type(4))) float f32x4;

__device__ __forceinline__ float sigf(float x)  { return 1.0f / (1.0f + __expf(-x)); }
__device__ __forceinline__ float tanhfast(float x) { return 1.0f - 2.0f / (__expf(2.0f * x) + 1.0f); }

// round-to-nearest-even fp32 -> bf16 (as raw ushort)
__device__ __forceinline__ unsigned short bf16hi(float f) {
    unsigned u = __float_as_uint(f);
    return (unsigned short)((u + 0x7fffu + ((u >> 16) & 1u)) >> 16);
}
__device__ __forceinline__ float bf16tof(unsigned short s) {
    return __uint_as_float(((unsigned)s) << 16);
}

// One block = 16 batch rows, ALL 512 steps, both LSTM layers + MLP head.
// Per tick one fused MFMA matmul: gates[16x416] = A[16x128] x B[128x416].
//   A K-layout: k 0..49 = h0(t-1) , k 50..99 = h1(t-2), k 100..127 = 0.
//   B N-layout: cols 0..199 = W_hh0 rows (layer0 gates), 200..207 = 0 pad,
//               cols 208..407 = [W_ih1; W_hh1] rows (layer1 gates), 408..415 = 0.
// Precision: 3-term split-bf16 EFT (hi*whi + lo*whi + hi*wlo), fp32 acc, fp32 c.
// Weights live as per-wave REGISTER B-fragments -> consumed directly by MFMA,
// so AGPR-parking by the allocator (rounds 2-7 pathology) is harmless.
__global__ __launch_bounds__(512, 2)
void lstm2_mfma_kernel(const float* __restrict__ x,
                       const float* __restrict__ W_ih0, const float* __restrict__ W_hh0,
                       const float* __restrict__ b_ih0, const float* __restrict__ b_hh0,
                       const float* __restrict__ W_ih1, const float* __restrict__ W_hh1,
                       const float* __restrict__ b_ih1, const float* __restrict__ b_hh1,
                       const float* __restrict__ W1, const float* __restrict__ b1,
                       const float* __restrict__ W2, const float* __restrict__ b2,
                       const float* __restrict__ W3, const float* __restrict__ b3,
                       float* __restrict__ out)
{
    const int tid  = threadIdx.x;
    const int lane = tid & 63;
    const int wid  = tid >> 6;           // 0..7
    const int l15  = lane & 15;
    const int grp8 = (lane >> 4) * 8;    // k-offset of this lane's 8-elem A/B slice
    const int b0   = blockIdx.x * BT;

    __shared__ float          xs[BT][XSS];        // x chunk [row][tick&63]
    __shared__ unsigned short Ah[BT][AK];         // h split hi (bf16), [row][k]
    __shared__ unsigned short Al[BT][AK];         // h split lo
    __shared__ float          gates[BT][GS];      // fused gate pre-activations
    __shared__ float          h1f[BT][52];        // final-layer h, fp32 (for MLP)
    __shared__ float          bias0s[200], bias1s[200], wih0s[200];
    __shared__ float          D1[BT][32], D2[BT][16];

    // ---- one-time staging ----
    if (tid < 200) {
        bias0s[tid] = b_ih0[tid] + b_hh0[tid];
        bias1s[tid] = b_ih1[tid] + b_hh1[tid];
        wih0s[tid]  = W_ih0[tid];
    }
    for (int i = tid; i < BT * AK; i += 512) {
        ((unsigned short*)Ah)[i] = 0;
        ((unsigned short*)Al)[i] = 0;
    }

    // ---- per-wave N-tile assignment (26 tiles of 16 cols; balanced by K-chunk count:
    //      tiles 0..12 have 2 valid K-chunks, tiles 13..25 have 4) ----
    int t0, t1, t2, t3;
    if      (wid < 5)  { t0 = 13 + 2 * wid; t1 = 14 + 2 * wid; t2 = wid; t3 = -1; }
    else if (wid == 5) { t0 = 23; t1 = 5;  t2 = 6;  t3 = 7;  }
    else if (wid == 6) { t0 = 24; t1 = 8;  t2 = 9;  t3 = 10; }
    else               { t0 = 25; t1 = 11; t2 = 12; t3 = -1; }
    const int tiles[4] = {t0, t1, t2, t3};

    // ---- build stationary B-fragments in registers (hi and lo copies) ----
    // B-frag layout (16x16x32): lane holds B[k = 32c + grp8 + j][col = 16*tile + l15]
    bf16x8 wHi[4][4], wLo[4][4];
#pragma unroll
    for (int s = 0; s < 4; ++s) {
        const int tl = tiles[s];
        if (tl < 0) continue;
        const int nc   = (tl < 13) ? 2 : 4;
        const int colv = tl * 16 + l15;
#pragma unroll
        for (int c = 0; c < 4; ++c) {
            if (c >= nc) continue;
#pragma unroll
            for (int j = 0; j < 8; ++j) {
                const int kk = 32 * c + grp8 + j;
                float wv = 0.0f;
                if (colv < 200) {                       // layer0: W_hh0, K = h0 only
                    if (kk < 50) wv = W_hh0[colv * 50 + kk];
                } else if (colv >= 208 && colv < 408) { // layer1: [W_ih1; W_hh1]
                    const int g1 = colv - 208;
                    if      (kk < 50)  wv = W_ih1[g1 * 50 + kk];
                    else if (kk < 100) wv = W_hh1[g1 * 50 + (kk - 50)];
                }
                const unsigned short h = bf16hi(wv);
                wHi[s][c][j] = (short)h;
                wLo[s][c][j] = (short)bf16hi(wv - bf16tof(h));
            }
        }
    }

    float cst[4] = {0.f, 0.f, 0.f, 0.f};   // per-thread c-state for up to 4 (layer,row,unit)
    __syncthreads();

    // ---- main recurrence: tau = 0..512 (513 ticks, 1-step layer skew) ----
    for (int tau = 0; tau <= TT; ++tau) {
        // refill x chunk every 64 ticks (consumed by pw AFTER the mid-tick barrier)
        if ((tau & (XC - 1)) == 0 && tau < TT && tid < 256) {
            const int r = tid >> 4, q = tid & 15;
            const float4 v = *(const float4*)&x[(size_t)(b0 + r) * TT + tau + 4 * q];
            xs[r][4 * q + 0] = v.x; xs[r][4 * q + 1] = v.y;
            xs[r][4 * q + 2] = v.z; xs[r][4 * q + 3] = v.w;
        }

        // ================= M phase: fused MFMA matmul =================
        bf16x8 ah[4], al[4];
#pragma unroll
        for (int c = 0; c < 4; ++c) {
            ah[c] = *(const bf16x8*)&Ah[l15][32 * c + grp8];
            al[c] = *(const bf16x8*)&Al[l15][32 * c + grp8];
        }
        f32x4 acc[4];
#pragma unroll
        for (int s = 0; s < 4; ++s)
#pragma unroll
            for (int r = 0; r < 4; ++r) acc[s][r] = 0.0f;

#pragma unroll
        for (int s = 0; s < 4; ++s) {
            const int tl = tiles[s];
            if (tl < 0) continue;
            const int nc = (tl < 13) ? 2 : 4;
#pragma unroll
            for (int c = 0; c < 4; ++c) {
                if (c >= nc) continue;
                acc[s] = __builtin_amdgcn_mfma_f32_16x16x32_bf16(ah[c], wHi[s][c], acc[s], 0, 0, 0);
                acc[s] = __builtin_amdgcn_mfma_f32_16x16x32_bf16(al[c], wHi[s][c], acc[s], 0, 0, 0);
                acc[s] = __builtin_amdgcn_mfma_f32_16x16x32_bf16(ah[c], wLo[s][c], acc[s], 0, 0, 0);
            }
        }
        // C layout (m89-verified): col = lane&15, row = (lane>>4)*4 + reg
#pragma unroll
        for (int s = 0; s < 4; ++s) {
            const int tl = tiles[s];
            if (tl < 0) continue;
            const int col = tl * 16 + l15;
#pragma unroll
            for (int r = 0; r < 4; ++r)
                gates[(lane >> 4) * 4 + r][col] = acc[s][r];
        }
        __syncthreads();

        // ================= P phase: pointwise (1600 (layer,row,unit) pairs) =================
#pragma unroll
        for (int p = 0; p < 4; ++p) {
            const bool on = (p < 3) || (tid < 64);
            if (on) {
                const int q    = (p < 3) ? (tid + (p << 9)) : (1536 + tid);
                const int lay  = (q >= 800) ? 1 : 0;
                const int qq   = lay ? q - 800 : q;
                const int row  = qq & 15;
                const int unit = qq >> 4;
                const bool doit = lay ? (tau >= 1) : (tau < TT);
                if (doit) {
                    const int cb = lay ? 208 : 0;
                    float g0 = gates[row][cb + unit];
                    float g1 = gates[row][cb + 50 + unit];
                    float g2 = gates[row][cb + 100 + unit];
                    float g3 = gates[row][cb + 150 + unit];
                    if (!lay) {
                        const float xv = xs[row][tau & (XC - 1)];
                        g0 = fmaf(xv, wih0s[unit],       g0) + bias0s[unit];
                        g1 = fmaf(xv, wih0s[50 + unit],  g1) + bias0s[50 + unit];
                        g2 = fmaf(xv, wih0s[100 + unit], g2) + bias0s[100 + unit];
                        g3 = fmaf(xv, wih0s[150 + unit], g3) + bias0s[150 + unit];
                    } else {
                        g0 += bias1s[unit];        g1 += bias1s[50 + unit];
                        g2 += bias1s[100 + unit];  g3 += bias1s[150 + unit];
                    }
                    const float ig = sigf(g0), fg = sigf(g1);
                    const float gg = tanhfast(g2), og = sigf(g3);
                    cst[p] = fmaf(fg, cst[p], ig * gg);
                    const float h = og * tanhfast(cst[p]);
                    const unsigned short hh = bf16hi(h);
                    const int kpos = lay ? (50 + unit) : unit;
                    Ah[row][kpos] = hh;
                    Al[row][kpos] = bf16hi(h - bf16tof(hh));
                    if (lay) h1f[row][unit] = h;
                }
            }
        }
        __syncthreads();
    }

    // ================= MLP head: 50 -> 32 -> 16 -> 1 =================
    {
        const int r = tid >> 5, o = tid & 31;       // 512 threads = 16x32
        float z = b1[o];
#pragma unroll
        for (int k = 0; k < HH; ++k) z = fmaf(W1[o * HH + k], h1f[r][k], z);
        D1[r][o] = fmaxf(z, 0.0f);
    }
    __syncthreads();
    if (tid < 256) {
        const int r = tid >> 4, o = tid & 15;
        float z = b2[o];
#pragma unroll
        for (int k = 0; k < 32; ++k) z = fmaf(W2[o * 32 + k], D1[r][k], z);
        D2[r][o] = fmaxf(z, 0.0f);
    }
    __syncthreads();
    if (tid < BT) {
        float z = b3[0];
#pragma unroll
        for (int k = 0; k < 16; ++k) z = fmaf(W3[k], D2[tid][k], z);
        out[b0 + tid] = z;
    }
}

extern "C" void kernel_launch(void* const* d_in, const int* in_sizes, int n_in,
                              void* d_out, int out_size, void* d_ws, size_t ws_size,
                              hipStream_t stream) {
    const float* x     = (const float*)d_in[0];
    const float* W_ih0 = (const float*)d_in[1];
    const float* W_hh0 = (const float*)d_in[2];
    const float* b_ih0 = (const float*)d_in[3];
    const float* b_hh0 = (const float*)d_in[4];
    const float* W_ih1 = (const float*)d_in[5];
    const float* W_hh1 = (const float*)d_in[6];
    const float* b_ih1 = (const float*)d_in[7];
    const float* b_hh1 = (const float*)d_in[8];
    const float* W1    = (const float*)d_in[9];
    const float* b1    = (const float*)d_in[10];
    const float* W2    = (const float*)d_in[11];
    const float* b2    = (const float*)d_in[12];
    const float* W3    = (const float*)d_in[13];
    const float* b3    = (const float*)d_in[14];

    const int B = in_sizes[0] / TT;     // x is [B, T, 1]
    const int nblocks = B / BT;         // 4096/16 = 256

    lstm2_mfma_kernel<<<dim3(nblocks), dim3(512), 0, stream>>>(
        x, W_ih0, W_hh0, b_ih0, b_hh0, W_ih1, W_hh1, b_ih1, b_hh1,
        W1, b1, W2, b2, W3, b3, (float*)d_out);
}

// Round 10
// 1057.398 us; speedup vs baseline: 8.3699x; 1.1454x over previous
//
#include <hip/hip_runtime.h>

#define TT 512
#define HH 50
#define BT 16
#define AK 136    // A(h) row stride in bf16 elems. MUST be >= 128: layer1 chunk-3
                  // b128 reads touch k=96..127 (zero-weighted guard region, zeroed
                  // once, never rewritten). Round-9 bug: AK=104 made these reads
                  // OOB -> undefined LDS -> bf16-NaN patterns -> 0*NaN=NaN ->
                  // nondeterministic output (tripwire). Banking: stride 68 dwords
                  // == 4 (mod 32) -> quad=(l15+gp)%8, same 2-way profile as 104.

typedef __attribute__((ext_vector_type(8))) short bf16x8;
typedef __attribute__((ext_vector_type(4))) short s16x4;
typedef __attribute__((ext_vector_type(2))) short s16x2;
typedef __attribute__((ext_vector_type(4))) float f32x4;

__device__ __forceinline__ float sigf(float x)     { return 1.0f / (1.0f + __expf(-x)); }
__device__ __forceinline__ float tanhfast(float x) { return 1.0f - 2.0f / (__expf(2.0f * x) + 1.0f); }

__device__ __forceinline__ unsigned short bf16hi(float f) {   // RNE fp32->bf16
    unsigned u = __float_as_uint(f);
    return (unsigned short)((u + 0x7fffu + ((u >> 16) & 1u)) >> 16);
}
__device__ __forceinline__ float bf16tof(unsigned short s) {
    return __uint_as_float(((unsigned)s) << 16);
}

// One block = 16 batch rows, full 512-step 2-layer recurrence + MLP head.
// OPERAND-SWAPPED MFMA: A = weights (stationary register fragments),
// B = hidden state (LDS, double-buffered). C[m=weight-row][n=batch-row]:
// tile M-row rr -> gate (rr&3) of unit ubase+(rr>>2)*4+s, so lane (gp,l15)
// reg r of acc[s] = gate r, unit ubase+4*gp+s, batch row l15: the FULL
// pointwise for 4 (unit,row) pairs is lane-local -> no gates LDS, 1 barrier
// per tick, h written as one b64 (4 consecutive k-slots).
// B K-layout: k0..49 h0(t-1) | k50 x-split | k51 const 1.0 | k52..101 h1(t-2)
//             | k102..135 zero guard (read by chunk 3, zero-weighted).
// x and biases are folded into the matmul via k50/k51 (3-term EFT covers them).
// Waves 0..3 = layer0 (chunks 0,1 = 24 MFMA), waves 4..7 = layer1 (chunks
// 0..3 = 48 MFMA); w%4 SIMD placement balances one of each per SIMD.
__global__ __launch_bounds__(512, 2)
void lstm2_mfma2_kernel(const float* __restrict__ x,
                        const float* __restrict__ W_ih0, const float* __restrict__ W_hh0,
                        const float* __restrict__ b_ih0, const float* __restrict__ b_hh0,
                        const float* __restrict__ W_ih1, const float* __restrict__ W_hh1,
                        const float* __restrict__ b_ih1, const float* __restrict__ b_hh1,
                        const float* __restrict__ W1, const float* __restrict__ b1,
                        const float* __restrict__ W2, const float* __restrict__ b2,
                        const float* __restrict__ W3, const float* __restrict__ b3,
                        float* __restrict__ out)
{
    const int tid   = threadIdx.x;
    const int lane  = tid & 63;
    const int wid   = tid >> 6;          // 0..7
    const int gp    = lane >> 4;         // 0..3
    const int l15   = lane & 15;
    const int grp8  = gp * 8;
    const int layer = wid >> 2;          // 0 or 1
    const int ubase = (wid & 3) * 16;
    const int b0    = blockIdx.x * BT;

    __shared__ unsigned short Ah[2][BT][AK];   // h image hi (bf16), double-buffered
    __shared__ unsigned short Al[2][BT][AK];   // h image lo
    __shared__ float h1f[BT][52];              // final h1 (fp32) for the MLP head
    __shared__ float D1[BT][32], D2[BT][16];

    // ---- zero-init both A buffers INCLUDING the k=102..135 guard ----
    {
        unsigned* az = (unsigned*)Ah;
        unsigned* bz = (unsigned*)Al;
        for (int i = tid; i < 2 * BT * (AK / 2); i += 512) { az[i] = 0u; bz[i] = 0u; }
    }

    // ---- stationary weight A-fragments (hi/lo), built once ----
    // A-frag: lane supplies A[m = l15][k = 32*chunk + grp8 + j].
    // m -> gate = l15&3, unit = ubase + (l15>>2)*4 + s.
    const int gateA = l15 & 3;
    const int unitA = ubase + (l15 >> 2) * 4;   // + s per tile
    bf16x8 wHi[4][4], wLo[4][4];
#pragma unroll
    for (int s = 0; s < 4; ++s) {
#pragma unroll
        for (int c = 0; c < 4; ++c) {
            if (layer == 0 && c >= 2) continue;     // layer0 uses chunks 0,1 only
            const int u  = unitA + s;
            const int gu = gateA * HH + u;
#pragma unroll
            for (int j = 0; j < 8; ++j) {
                const int kk = 32 * c + grp8 + j;
                float wv = 0.0f;
                if (u < HH) {
                    if (layer == 0) {
                        if      (kk < 50)  wv = W_hh0[gu * HH + kk];
                        else if (kk == 50) wv = W_ih0[gu];
                        else if (kk == 51) wv = b_ih0[gu] + b_hh0[gu];
                    } else {
                        if      (kk < 50)  wv = W_ih1[gu * HH + kk];
                        else if (kk == 51) wv = b_ih1[gu] + b_hh1[gu];
                        else if (kk >= 52 && kk < 102) wv = W_hh1[gu * HH + (kk - 52)];
                    }
                }
                const unsigned short h = bf16hi(wv);
                wHi[s][c][j] = (short)h;
                wLo[s][c][j] = (short)bf16hi(wv - bf16tof(h));
            }
        }
    }

    __syncthreads();
    // const-1 slot (k=51) in both buffers; x(0) into buffer 0
    if (tid < 32) Ah[tid >> 4][tid & 15][51] = 0x3F80;   // bf16(1.0)
    if (tid < BT) {
        const float xv = x[(size_t)(b0 + tid) * TT];
        const unsigned short xh = bf16hi(xv);
        Ah[0][tid][50] = xh;
        Al[0][tid][50] = bf16hi(xv - bf16tof(xh));
    }
    __syncthreads();

    float cst[4] = {0.f, 0.f, 0.f, 0.f};
    const int u0 = ubase + 4 * gp;          // first unit of this lane's pack
    const int nv = (u0 + 3 < HH) ? 4 : ((u0 < HH) ? 2 : 0);

    for (int tau = 0; tau <= TT; ++tau) {
        const int cur = tau & 1, nxt = cur ^ 1;
        const bool active = layer ? (tau >= 1) : (tau < TT);
        const bool xduty  = (wid == 3 && gp == 1 && tau < TT - 1);

        float xv = 0.0f;
        if (xduty) xv = x[(size_t)(b0 + l15) * TT + (tau + 1)];   // hidden under MFMA

        if (active) {
            // ---- B-fragments: h image, lane supplies B[k][n = l15] ----
            bf16x8 bh0, bh1, bh2, bh3, bl0, bl1, bl2, bl3;
            bh0 = *(const bf16x8*)&Ah[cur][l15][grp8];
            bh1 = *(const bf16x8*)&Ah[cur][l15][32 + grp8];
            bl0 = *(const bf16x8*)&Al[cur][l15][grp8];
            bl1 = *(const bf16x8*)&Al[cur][l15][32 + grp8];
            if (layer) {
                bh2 = *(const bf16x8*)&Ah[cur][l15][64 + grp8];
                bh3 = *(const bf16x8*)&Ah[cur][l15][96 + grp8];
                bl2 = *(const bf16x8*)&Al[cur][l15][64 + grp8];
                bl3 = *(const bf16x8*)&Al[cur][l15][96 + grp8];
            }

            f32x4 acc[4];
#pragma unroll
            for (int s = 0; s < 4; ++s) { acc[s][0] = acc[s][1] = acc[s][2] = acc[s][3] = 0.f; }

#define EFT(S, C, BH, BL)                                                              \
    acc[S] = __builtin_amdgcn_mfma_f32_16x16x32_bf16(wHi[S][C], BH, acc[S], 0, 0, 0);  \
    acc[S] = __builtin_amdgcn_mfma_f32_16x16x32_bf16(wHi[S][C], BL, acc[S], 0, 0, 0);  \
    acc[S] = __builtin_amdgcn_mfma_f32_16x16x32_bf16(wLo[S][C], BH, acc[S], 0, 0, 0);

            EFT(0,0,bh0,bl0) EFT(1,0,bh0,bl0) EFT(2,0,bh0,bl0) EFT(3,0,bh0,bl0)
            EFT(0,1,bh1,bl1) EFT(1,1,bh1,bl1) EFT(2,1,bh1,bl1) EFT(3,1,bh1,bl1)
            if (layer) {
                EFT(0,2,bh2,bl2) EFT(1,2,bh2,bl2) EFT(2,2,bh2,bl2) EFT(3,2,bh2,bl2)
                EFT(0,3,bh3,bl3) EFT(1,3,bh3,bl3) EFT(2,3,bh3,bl3) EFT(3,3,bh3,bl3)
            }
#undef EFT

            // ---- pointwise: fully lane-local (gates = acc[s][0..3]) ----
            unsigned short hh[4], hl[4];
            float hf[4];
#pragma unroll
            for (int s = 0; s < 4; ++s) {
                const float ig = sigf(acc[s][0]);
                const float fg = sigf(acc[s][1]);
                const float gg = tanhfast(acc[s][2]);
                const float og = sigf(acc[s][3]);
                cst[s] = fmaf(fg, cst[s], ig * gg);
                const float h = og * tanhfast(cst[s]);
                hf[s] = h;
                hh[s] = bf16hi(h);
                hl[s] = bf16hi(h - bf16tof(hh[s]));
            }

            const int kpos = (layer ? 52 : 0) + u0;
            if (nv == 4) {
                *(s16x4*)&Ah[nxt][l15][kpos] = (s16x4){(short)hh[0], (short)hh[1], (short)hh[2], (short)hh[3]};
                *(s16x4*)&Al[nxt][l15][kpos] = (s16x4){(short)hl[0], (short)hl[1], (short)hl[2], (short)hl[3]};
            } else if (nv == 2) {
                *(s16x2*)&Ah[nxt][l15][kpos] = (s16x2){(short)hh[0], (short)hh[1]};
                *(s16x2*)&Al[nxt][l15][kpos] = (s16x2){(short)hl[0], (short)hl[1]};
            }
            if (layer && tau == TT && nv) {
                if (nv == 4) *(float4*)&h1f[l15][u0] = make_float4(hf[0], hf[1], hf[2], hf[3]);
                else         { h1f[l15][u0] = hf[0]; h1f[l15][u0 + 1] = hf[1]; }
            }
        }

        if (xduty) {
            const unsigned short xh = bf16hi(xv);
            Ah[nxt][l15][50] = xh;
            Al[nxt][l15][50] = bf16hi(xv - bf16tof(xh));
        }
        __syncthreads();
    }

    // ================= MLP head: 50 -> 32 -> 16 -> 1 =================
    {
        const int r = tid >> 5, o = tid & 31;       // 512 threads = 16x32
        float z = b1[o];
#pragma unroll
        for (int k = 0; k < HH; ++k) z = fmaf(W1[o * HH + k], h1f[r][k], z);
        D1[r][o] = fmaxf(z, 0.0f);
    }
    __syncthreads();
    if (tid < 256) {
        const int r = tid >> 4, o = tid & 15;
        float z = b2[o];
#pragma unroll
        for (int k = 0; k < 32; ++k) z = fmaf(W2[o * 32 + k], D1[r][k], z);
        D2[r][o] = fmaxf(z, 0.0f);
    }
    __syncthreads();
    if (tid < BT) {
        float z = b3[0];
#pragma unroll
        for (int k = 0; k < 16; ++k) z = fmaf(W3[k], D2[tid][k], z);
        out[b0 + tid] = z;
    }
}

extern "C" void kernel_launch(void* const* d_in, const int* in_sizes, int n_in,
                              void* d_out, int out_size, void* d_ws, size_t ws_size,
                              hipStream_t stream) {
    const float* x     = (const float*)d_in[0];
    const float* W_ih0 = (const float*)d_in[1];
    const float* W_hh0 = (const float*)d_in[2];
    const float* b_ih0 = (const float*)d_in[3];
    const float* b_hh0 = (const float*)d_in[4];
    const float* W_ih1 = (const float*)d_in[5];
    const float* W_hh1 = (const float*)d_in[6];
    const float* b_ih1 = (const float*)d_in[7];
    const float* b_hh1 = (const float*)d_in[8];
    const float* W1    = (const float*)d_in[9];
    const float* b1    = (const float*)d_in[10];
    const float* W2    = (const float*)d_in[11];
    const float* b2    = (const float*)d_in[12];
    const float* W3    = (const float*)d_in[13];
    const float* b3    = (const float*)d_in[14];

    const int B = in_sizes[0] / TT;     // x is [B, T, 1]
    const int nblocks = B / BT;         // 4096/16 = 256

    lstm2_mfma2_kernel<<<dim3(nblocks), dim3(512), 0, stream>>>(
        x, W_ih0, W_hh0, b_ih0, b_hh0, W_ih1, W_hh1, b_ih1, b_hh1,
        W1, b1, W2, b2, W3, b3, (float*)d_out);
}